// Round 12
// baseline (888.168 us; speedup 1.0000x reference)
//
#include <hip/hip_runtime.h>

#define N_NODES 50000
#define N_PAD   50048        // padded (xb pad rows incl. zero row; cursor pad)
#define N_EDGES 600000
#define IN_F 128
#define HID 256
#define OUT_F 64
#define ROWS 16              // nodes per tile; 50000/16 = 3125 tiles exactly
#define SLOTS 56             // fixed bucket slots/node; P(deg>=56|Poisson(12))~1e-24
#define NTILE (N_NODES / ROWS)   // 3125
#define GRID  1536           // 6 blocks/CU x 256 CUs -- GUARANTEED co-resident:
                             // LDS 20KB (cap 8/CU), 24 waves/CU (cap 32),
                             // VGPR <=85 via __launch_bounds__(256,6)
#define NTHR  (GRID * 256)   // 393216 threads
#define ZERO_ROW N_NODES     // xb row 50000 is zeroed; padded gather slots read it

typedef __attribute__((ext_vector_type(8))) short bf16x8;
typedef __attribute__((ext_vector_type(4))) float f32x4;

__device__ inline short f2bf(float f) {   // RNE float->bf16 bits
    unsigned u = __builtin_bit_cast(unsigned, f);
    u += 0x7fffu + ((u >> 16) & 1u);
    return (short)(u >> 16);
}
__device__ inline float bflo(unsigned u) { return __builtin_bit_cast(float, u << 16); }
__device__ inline float bfhi(unsigned u) { return __builtin_bit_cast(float, u & 0xffff0000u); }

// ---------------------------------------------------------------------------
// Device-scope grid barrier (all GRID blocks are co-resident by construction).
// Release: __threadfence + ACQ_REL atomic add (agent scope) publishes this
// block's writes across XCD L2s. Acquire: spin on agent-scope atomic load.
// Counters are memset to 0 at the top of every launch (graph-captured).
// ---------------------------------------------------------------------------
__device__ inline void grid_sync(int* cnt) {
    __syncthreads();
    if (threadIdx.x == 0) {
        __threadfence();
        __hip_atomic_fetch_add(cnt, 1, __ATOMIC_ACQ_REL, __HIP_MEMORY_SCOPE_AGENT);
        while (__hip_atomic_load(cnt, __ATOMIC_ACQUIRE, __HIP_MEMORY_SCOPE_AGENT) < GRID)
            __builtin_amdgcn_s_sleep(8);
    }
    __syncthreads();
}

// ---------------------------------------------------------------------------
// LDS helper for the 16x256 Hs tiles (16B-chunk XOR swizzle)
// ---------------------------------------------------------------------------
__device__ inline bf16x8 afrag_lds256(const short* S, int lane, int ks) {
    int row = lane & 15, g = lane >> 4;
    int chunk = (ks * 4 + g) ^ row;
    return *reinterpret_cast<const bf16x8*>(
        reinterpret_cast<const char*>(S) + row * 512 + chunk * 16);
}

// ---------------------------------------------------------------------------
// MEGA kernel: phase A (prep) -> sync -> phase B (build) -> sync -> phase C
// (fused gather+MLP, grid-strided over 3125 tiles).
//   A: x fp32->bf16 (grid-stride); weight frags F1a/F1b/Fc(=Wsg@W2a)/F2b;
//      zero cursor; zero xb pad rows.
//   B: bucket fill esrc[dst*56+p]=src (atomics run phase-exclusive).
//   C: per tile: gather-mean->Ms; dual stage1 (x@W1a || Ms@Wc) -> Hs1,Hs2;
//      dual stage2 (Hs1@W1b || Hs2@W2b); out = o1+o2+b1b+b2b.
// ---------------------------------------------------------------------------
__global__ __launch_bounds__(256, 6) void mega_kernel(
    const float* __restrict__ x, const int* __restrict__ ei,
    const float* __restrict__ Wsg, const float* __restrict__ W2a,
    const float* __restrict__ W1a, const float* __restrict__ W1b,
    const float* __restrict__ W2b,
    const float* __restrict__ b1a, const float* __restrict__ b1b,
    const float* __restrict__ b2a, const float* __restrict__ b2b,
    short* __restrict__ xb, unsigned short* __restrict__ esrc,
    int* __restrict__ cursor,
    short* __restrict__ F1a, short* __restrict__ F1b,
    short* __restrict__ Fc,  short* __restrict__ F2b,
    int* __restrict__ sync_cnt, float* __restrict__ out)
{
    __shared__ short Ms[16 * 128];    // 4 KB
    __shared__ short Hs1[16 * 256];   // 8 KB
    __shared__ short Hs2[16 * 256];   // 8 KB
    const int t = threadIdx.x, w = t >> 6, lane = t & 63;
    const int gtid = blockIdx.x * 256 + t;
    const int row16 = lane & 15, g = lane >> 4;

    // ================= phase A: prep =================
    // x fp32 -> bf16, one 8-elem chunk per iteration (800000 chunks)
    for (int i = gtid; i < N_NODES * IN_F / 8; i += NTHR) {
        float4 a0 = *reinterpret_cast<const float4*>(x + (size_t)i * 8);
        float4 a1 = *reinterpret_cast<const float4*>(x + (size_t)i * 8 + 4);
        bf16x8 v;
        v[0] = f2bf(a0.x); v[1] = f2bf(a0.y); v[2] = f2bf(a0.z); v[3] = f2bf(a0.w);
        v[4] = f2bf(a1.x); v[5] = f2bf(a1.y); v[6] = f2bf(a1.z); v[7] = f2bf(a1.w);
        *reinterpret_cast<bf16x8*>(xb + (size_t)i * 8) = v;
    }
    if (gtid < 12288) {
        // weight chunk cid: lane=c&63, ks=(c>>6)%KST, nt=(c>>6)/KST;
        //   elem j: B[ks*32 + (lane>>4)*8 + j][nt*16 + (lane&15)]
        int cid = gtid;
        if (cid >= 6144 && cid < 10240) {
            // Fc chunk: Wc = Wsg @ W2a computed in fp32, then bf16 fragment
            int c = cid - 6144;
            int ln = c & 63, rem = c >> 6;
            int ks = rem & 3, nt = rem >> 2;
            int col = nt * 16 + (ln & 15);
            int k0 = ks * 32 + (ln >> 4) * 8;
            float acc[8] = {0.f, 0.f, 0.f, 0.f, 0.f, 0.f, 0.f, 0.f};
            for (int m0 = 0; m0 < 128; m0 += 8) {
                float wcol[8];
                #pragma unroll
                for (int mm = 0; mm < 8; ++mm)
                    wcol[mm] = W2a[(size_t)(m0 + mm) * HID + col];
                #pragma unroll
                for (int j = 0; j < 8; ++j)
                    #pragma unroll
                    for (int mm = 0; mm < 8; ++mm)
                        acc[j] = fmaf(Wsg[(size_t)(k0 + j) * IN_F + m0 + mm],
                                      wcol[mm], acc[j]);
            }
            bf16x8 v;
            #pragma unroll
            for (int j = 0; j < 8; ++j) v[j] = f2bf(acc[j]);
            *reinterpret_cast<bf16x8*>(Fc + (size_t)c * 8) = v;
        } else {
            const float* src; short* dst; int N, KST, base;
            if      (cid < 4096)  { src = W1a; dst = F1a; N = 256; KST = 4; base = 0; }
            else if (cid < 6144)  { src = W1b; dst = F1b; N = 64;  KST = 8; base = 4096; }
            else                  { src = W2b; dst = F2b; N = 64;  KST = 8; base = 10240; }
            int c = cid - base;
            int ln = c & 63, rem = c >> 6;
            int ks = rem % KST, nt = rem / KST;
            int col = nt * 16 + (ln & 15);
            int k0 = ks * 32 + (ln >> 4) * 8;
            bf16x8 v;
            #pragma unroll
            for (int j = 0; j < 8; ++j)
                v[j] = f2bf(src[(size_t)(k0 + j) * N + col]);
            *reinterpret_cast<bf16x8*>(dst + (size_t)c * 8) = v;
        }
    } else if (gtid < 13056) {
        // zero xb pad rows 50000..50047 (768 chunks)
        int i = gtid - 12288;
        bf16x8 z = {0, 0, 0, 0, 0, 0, 0, 0};
        *reinterpret_cast<bf16x8*>(xb + (size_t)N_NODES * IN_F + (size_t)i * 8) = z;
    } else if (gtid < 13056 + N_PAD) {
        cursor[gtid - 13056] = 0;
    }

    grid_sync(sync_cnt);

    // ================= phase B: build (atomics, phase-exclusive) =================
    for (int e = gtid; e < N_EDGES; e += NTHR) {
        int src = ei[e];
        int dst = ei[N_EDGES + e];
        int p = atomicAdd(&cursor[dst], 1);
        if (p < SLOTS) esrc[(size_t)dst * SLOTS + p] = (unsigned short)src;
    }

    grid_sync(sync_cnt + 16);

    // ================= phase C: fused gather + MLP, grid-strided tiles =======
    for (int tile = blockIdx.x; tile < NTILE; tile += GRID) {
        const long r0 = (long)tile * ROWS;

        // ---- gather-mean: wave w owns rows w*4..+3; lane owns 2 features.
        //      16 row-loads in flight/chunk; padded slots read the zero row. ----
        #pragma unroll
        for (int nn = 0; nn < 4; ++nn) {
            int row = w * 4 + nn;
            long node = r0 + row;
            int d = min(cursor[node], SLOTS);            // cursor == deg now
            int du = __builtin_amdgcn_readfirstlane(d);  // wave-uniform
            int slot = min(lane, SLOTS - 1);
            int my = esrc[(size_t)node * SLOTS + slot];  // coalesced 2B/lane
            float ax = 0.f, ay = 0.f;
            for (int j = 0; j < du; j += 16) {
                unsigned u[16];
                #pragma unroll
                for (int k = 0; k < 16; ++k) {
                    int idx = j + k;
                    int s = (idx < du) ? __builtin_amdgcn_readlane(my, idx)
                                       : ZERO_ROW;       // SALU cselect; zero row
                    u[k] = *reinterpret_cast<const unsigned*>(
                        xb + (size_t)s * IN_F + lane * 2);
                }
                #pragma unroll
                for (int k = 0; k < 16; ++k) {
                    ax += bflo(u[k]);                    // padded rows add 0
                    ay += bfhi(u[k]);
                }
            }
            float inv = (du > 0) ? 1.0f / (float)du : 0.0f;
            ax *= inv; ay *= inv;
            int chunk = (lane >> 2) ^ row;               // XOR swizzle
            unsigned packed = (unsigned)(unsigned short)f2bf(ax)
                            | ((unsigned)(unsigned short)f2bf(ay) << 16);
            *reinterpret_cast<unsigned*>(reinterpret_cast<char*>(Ms)
                + row * 256 + chunk * 16 + (lane & 3) * 4) = packed;
        }

        // ---- issue branch1 A-frag loads BEFORE the barrier (latency hides) ----
        bf16x8 afrA[4];
        {
            const short* xrow = xb + (size_t)(r0 + row16) * IN_F + g * 8;
            #pragma unroll
            for (int ks = 0; ks < 4; ++ks)
                afrA[ks] = *reinterpret_cast<const bf16x8*>(xrow + ks * 32);
        }
        __syncthreads();

        // ---- dual stage1: two independent MFMA chains per nt ----
        bf16x8 afrB[4];
        #pragma unroll
        for (int ks = 0; ks < 4; ++ks) {
            int row = lane & 15, gg = lane >> 4;
            int chunk = (ks * 4 + gg) ^ row;
            afrB[ks] = *reinterpret_cast<const bf16x8*>(
                reinterpret_cast<const char*>(Ms) + row * 256 + chunk * 16);
        }
        #pragma unroll
        for (int i = 0; i < 4; ++i) {
            int nt = w * 4 + i;
            bf16x8 bA[4], bB[4];
            #pragma unroll
            for (int ks = 0; ks < 4; ++ks) {
                bA[ks] = *reinterpret_cast<const bf16x8*>(
                    F1a + ((size_t)(nt * 4 + ks) * 64 + lane) * 8);
                bB[ks] = *reinterpret_cast<const bf16x8*>(
                    Fc + ((size_t)(nt * 4 + ks) * 64 + lane) * 8);
            }
            f32x4 acc1 = {0.f, 0.f, 0.f, 0.f};
            f32x4 acc2 = {0.f, 0.f, 0.f, 0.f};
            #pragma unroll
            for (int ks = 0; ks < 4; ++ks) {
                acc1 = __builtin_amdgcn_mfma_f32_16x16x32_bf16(afrA[ks], bA[ks], acc1, 0, 0, 0);
                acc2 = __builtin_amdgcn_mfma_f32_16x16x32_bf16(afrB[ks], bB[ks], acc2, 0, 0, 0);
            }
            int col = nt * 16 + row16;
            float bias1 = b1a[col], bias2 = b2a[col];
            #pragma unroll
            for (int reg = 0; reg < 4; ++reg) {
                int hrow = g * 4 + reg;
                int off = hrow * 512 + ((((col >> 3) ^ hrow) & 31) * 16) + (col & 7) * 2;
                *reinterpret_cast<short*>(reinterpret_cast<char*>(Hs1) + off)
                    = f2bf(fmaxf(acc1[reg] + bias1, 0.0f));
                *reinterpret_cast<short*>(reinterpret_cast<char*>(Hs2) + off)
                    = f2bf(fmaxf(acc2[reg] + bias2, 0.0f));
            }
        }
        __syncthreads();

        // ---- dual stage2 + single store (tiles exactly cover 50000 rows) ----
        f32x4 o1 = {0.f, 0.f, 0.f, 0.f};
        f32x4 o2 = {0.f, 0.f, 0.f, 0.f};
        #pragma unroll
        for (int ks = 0; ks < 8; ++ks) {
            bf16x8 a1 = afrag_lds256(Hs1, lane, ks);
            bf16x8 b1 = *reinterpret_cast<const bf16x8*>(
                F1b + ((size_t)(w * 8 + ks) * 64 + lane) * 8);
            o1 = __builtin_amdgcn_mfma_f32_16x16x32_bf16(a1, b1, o1, 0, 0, 0);
            bf16x8 a2 = afrag_lds256(Hs2, lane, ks);
            bf16x8 b2 = *reinterpret_cast<const bf16x8*>(
                F2b + ((size_t)(w * 8 + ks) * 64 + lane) * 8);
            o2 = __builtin_amdgcn_mfma_f32_16x16x32_bf16(a2, b2, o2, 0, 0, 0);
        }
        {
            int col = w * 16 + row16;
            float bias = b1b[col] + b2b[col];
            #pragma unroll
            for (int reg = 0; reg < 4; ++reg) {
                long row = r0 + g * 4 + reg;
                out[row * OUT_F + col] = o1[reg] + o2[reg] + bias;
            }
        }
        __syncthreads();   // Ms/Hs reuse safety across tile iterations
    }
}

// ---------------------------------------------------------------------------
extern "C" void kernel_launch(void* const* d_in, const int* in_sizes, int n_in,
                              void* d_out, int out_size, void* d_ws, size_t ws_size,
                              hipStream_t stream)
{
    const float* x   = (const float*)d_in[0];
    const int*   ei  = (const int*)d_in[1];
    const float* Wsg = (const float*)d_in[2];
    const float* W1a = (const float*)d_in[3];
    const float* b1a = (const float*)d_in[4];
    const float* W1b = (const float*)d_in[5];
    const float* b1b = (const float*)d_in[6];
    const float* W2a = (const float*)d_in[7];
    const float* b2a = (const float*)d_in[8];
    const float* W2b = (const float*)d_in[9];
    const float* b2b = (const float*)d_in[10];
    float* out = (float*)d_out;

    // workspace layout (all 16B-aligned): ~18.8 MB total
    int* cursor = (int*)d_ws;                              // [N_PAD] (200 KB)
    unsigned short* esrc = (unsigned short*)(cursor + N_PAD);  // [N_PAD*56] = 5.6 MB
    short* F1a = (short*)(esrc + (size_t)N_PAD * SLOTS);   // 4096 chunks (64 KB)
    short* F1b = F1a + 4096 * 8;                           // 2048 chunks (32 KB)
    short* Fc  = F1b + 2048 * 8;                           // 4096 chunks (64 KB)
    short* F2b = Fc + 4096 * 8;                            // 2048 chunks (32 KB)
    short* xb  = F2b + 2048 * 8;                           // [N_PAD*128] bf16 (12.8 MB)
    int* sync_cnt = (int*)(xb + (size_t)N_PAD * IN_F);     // [64] barrier counters

    hipMemsetAsync(sync_cnt, 0, 256, stream);              // reset barrier counters
    mega_kernel<<<GRID, 256, 0, stream>>>(x, ei, Wsg, W2a, W1a, W1b, W2b,
                                          b1a, b1b, b2a, b2b,
                                          xb, esrc, cursor,
                                          F1a, F1b, Fc, F2b,
                                          sync_cnt, out);
}

// Round 13
// 455.430 us; speedup vs baseline: 1.9502x; 1.9502x over previous
//
#include <hip/hip_runtime.h>

#define N_NODES 50000
#define N_PAD   50048        // padded (xb pad rows incl. zero row; cursor pad)
#define N_EDGES 600000
#define IN_F 128
#define HID 256
#define OUT_F 64
#define ROWS 16              // nodes per tile; 50000/16 = 3125 tiles exactly
#define SLOTS 56             // fixed bucket slots/node; P(deg>=56|Poisson(12))~1e-24
#define NTILE (N_NODES / ROWS)   // 3125
#define GRID  1024           // 4 blocks/CU x 256 CUs -- co-resident by construction:
                             // LDS 20KB (cap 8/CU), 16 waves/CU (cap 32),
                             // VGPR cap 128 via __launch_bounds__(256,4) >> ~60 needed
                             // (round-12 lesson: (256,6) capped VGPR at 85->40,
                             //  spilled u[16] -> 237MB scratch writes, 8x slowdown)
#define NTHR  (GRID * 256)   // 262144 threads
#define ZERO_ROW N_NODES     // xb row 50000 is zeroed; padded gather slots read it

typedef __attribute__((ext_vector_type(8))) short bf16x8;
typedef __attribute__((ext_vector_type(4))) float f32x4;

__device__ inline short f2bf(float f) {   // RNE float->bf16 bits
    unsigned u = __builtin_bit_cast(unsigned, f);
    u += 0x7fffu + ((u >> 16) & 1u);
    return (short)(u >> 16);
}
__device__ inline float bflo(unsigned u) { return __builtin_bit_cast(float, u << 16); }
__device__ inline float bfhi(unsigned u) { return __builtin_bit_cast(float, u & 0xffff0000u); }

// ---------------------------------------------------------------------------
// Device-scope grid barrier (all GRID blocks co-resident by construction).
// Release: __threadfence + ACQ_REL atomic add (agent scope) publishes this
// block's writes across XCD L2s. Acquire: spin on agent-scope atomic load.
// Counters are memset to 0 at the top of every launch (graph-captured).
// ---------------------------------------------------------------------------
__device__ inline void grid_sync(int* cnt) {
    __syncthreads();
    if (threadIdx.x == 0) {
        __threadfence();
        __hip_atomic_fetch_add(cnt, 1, __ATOMIC_ACQ_REL, __HIP_MEMORY_SCOPE_AGENT);
        while (__hip_atomic_load(cnt, __ATOMIC_ACQUIRE, __HIP_MEMORY_SCOPE_AGENT) < GRID)
            __builtin_amdgcn_s_sleep(8);
    }
    __syncthreads();
}

// ---------------------------------------------------------------------------
// LDS helper for the 16x256 Hs tiles (16B-chunk XOR swizzle)
// ---------------------------------------------------------------------------
__device__ inline bf16x8 afrag_lds256(const short* S, int lane, int ks) {
    int row = lane & 15, g = lane >> 4;
    int chunk = (ks * 4 + g) ^ row;
    return *reinterpret_cast<const bf16x8*>(
        reinterpret_cast<const char*>(S) + row * 512 + chunk * 16);
}

// ---------------------------------------------------------------------------
// MEGA kernel: phase A (prep) -> sync -> phase B (build) -> sync -> phase C
// (fused gather+MLP, grid-strided over 3125 tiles).
//   A: x fp32->bf16 (grid-stride); weight frags F1a/F1b/Fc(=Wsg@W2a)/F2b;
//      zero cursor; zero xb pad rows.
//   B: bucket fill esrc[dst*56+p]=src (atomics run phase-exclusive).
//   C: per tile: gather-mean->Ms; dual stage1 (x@W1a || Ms@Wc) -> Hs1,Hs2;
//      dual stage2 (Hs1@W1b || Hs2@W2b); out = o1+o2+b1b+b2b.
// ---------------------------------------------------------------------------
__global__ __launch_bounds__(256, 4) void mega_kernel(
    const float* __restrict__ x, const int* __restrict__ ei,
    const float* __restrict__ Wsg, const float* __restrict__ W2a,
    const float* __restrict__ W1a, const float* __restrict__ W1b,
    const float* __restrict__ W2b,
    const float* __restrict__ b1a, const float* __restrict__ b1b,
    const float* __restrict__ b2a, const float* __restrict__ b2b,
    short* __restrict__ xb, unsigned short* __restrict__ esrc,
    int* __restrict__ cursor,
    short* __restrict__ F1a, short* __restrict__ F1b,
    short* __restrict__ Fc,  short* __restrict__ F2b,
    int* __restrict__ sync_cnt, float* __restrict__ out)
{
    __shared__ short Ms[16 * 128];    // 4 KB
    __shared__ short Hs1[16 * 256];   // 8 KB
    __shared__ short Hs2[16 * 256];   // 8 KB
    const int t = threadIdx.x, w = t >> 6, lane = t & 63;
    const int gtid = blockIdx.x * 256 + t;
    const int row16 = lane & 15, g = lane >> 4;

    // ================= phase A: prep =================
    // x fp32 -> bf16, one 8-elem chunk per iteration (800000 chunks)
    for (int i = gtid; i < N_NODES * IN_F / 8; i += NTHR) {
        float4 a0 = *reinterpret_cast<const float4*>(x + (size_t)i * 8);
        float4 a1 = *reinterpret_cast<const float4*>(x + (size_t)i * 8 + 4);
        bf16x8 v;
        v[0] = f2bf(a0.x); v[1] = f2bf(a0.y); v[2] = f2bf(a0.z); v[3] = f2bf(a0.w);
        v[4] = f2bf(a1.x); v[5] = f2bf(a1.y); v[6] = f2bf(a1.z); v[7] = f2bf(a1.w);
        *reinterpret_cast<bf16x8*>(xb + (size_t)i * 8) = v;
    }
    if (gtid < 12288) {
        // weight chunk cid: lane=c&63, ks=(c>>6)%KST, nt=(c>>6)/KST;
        //   elem j: B[ks*32 + (lane>>4)*8 + j][nt*16 + (lane&15)]
        int cid = gtid;
        if (cid >= 6144 && cid < 10240) {
            // Fc chunk: Wc = Wsg @ W2a computed in fp32, then bf16 fragment
            int c = cid - 6144;
            int ln = c & 63, rem = c >> 6;
            int ks = rem & 3, nt = rem >> 2;
            int col = nt * 16 + (ln & 15);
            int k0 = ks * 32 + (ln >> 4) * 8;
            float acc[8] = {0.f, 0.f, 0.f, 0.f, 0.f, 0.f, 0.f, 0.f};
            for (int m0 = 0; m0 < 128; m0 += 8) {
                float wcol[8];
                #pragma unroll
                for (int mm = 0; mm < 8; ++mm)
                    wcol[mm] = W2a[(size_t)(m0 + mm) * HID + col];
                #pragma unroll
                for (int j = 0; j < 8; ++j)
                    #pragma unroll
                    for (int mm = 0; mm < 8; ++mm)
                        acc[j] = fmaf(Wsg[(size_t)(k0 + j) * IN_F + m0 + mm],
                                      wcol[mm], acc[j]);
            }
            bf16x8 v;
            #pragma unroll
            for (int j = 0; j < 8; ++j) v[j] = f2bf(acc[j]);
            *reinterpret_cast<bf16x8*>(Fc + (size_t)c * 8) = v;
        } else {
            const float* src; short* dst; int N, KST, base;
            if      (cid < 4096)  { src = W1a; dst = F1a; N = 256; KST = 4; base = 0; }
            else if (cid < 6144)  { src = W1b; dst = F1b; N = 64;  KST = 8; base = 4096; }
            else                  { src = W2b; dst = F2b; N = 64;  KST = 8; base = 10240; }
            int c = cid - base;
            int ln = c & 63, rem = c >> 6;
            int ks = rem % KST, nt = rem / KST;
            int col = nt * 16 + (ln & 15);
            int k0 = ks * 32 + (ln >> 4) * 8;
            bf16x8 v;
            #pragma unroll
            for (int j = 0; j < 8; ++j)
                v[j] = f2bf(src[(size_t)(k0 + j) * N + col]);
            *reinterpret_cast<bf16x8*>(dst + (size_t)c * 8) = v;
        }
    } else if (gtid < 13056) {
        // zero xb pad rows 50000..50047 (768 chunks)
        int i = gtid - 12288;
        bf16x8 z = {0, 0, 0, 0, 0, 0, 0, 0};
        *reinterpret_cast<bf16x8*>(xb + (size_t)N_NODES * IN_F + (size_t)i * 8) = z;
    } else if (gtid < 13056 + N_PAD) {
        cursor[gtid - 13056] = 0;
    }

    grid_sync(sync_cnt);

    // ================= phase B: build (atomics, phase-exclusive) =================
    for (int e = gtid; e < N_EDGES; e += NTHR) {
        int src = ei[e];
        int dst = ei[N_EDGES + e];
        int p = atomicAdd(&cursor[dst], 1);
        if (p < SLOTS) esrc[(size_t)dst * SLOTS + p] = (unsigned short)src;
    }

    grid_sync(sync_cnt + 16);

    // ================= phase C: fused gather + MLP, grid-strided tiles =======
    for (int tile = blockIdx.x; tile < NTILE; tile += GRID) {
        const long r0 = (long)tile * ROWS;

        // ---- gather-mean: wave w owns rows w*4..+3; lane owns 2 features.
        //      16 row-loads in flight/chunk; padded slots read the zero row. ----
        #pragma unroll
        for (int nn = 0; nn < 4; ++nn) {
            int row = w * 4 + nn;
            long node = r0 + row;
            int d = min(cursor[node], SLOTS);            // cursor == deg now
            int du = __builtin_amdgcn_readfirstlane(d);  // wave-uniform
            int slot = min(lane, SLOTS - 1);
            int my = esrc[(size_t)node * SLOTS + slot];  // coalesced 2B/lane
            float ax = 0.f, ay = 0.f;
            for (int j = 0; j < du; j += 16) {
                unsigned u[16];
                #pragma unroll
                for (int k = 0; k < 16; ++k) {
                    int idx = j + k;
                    int s = (idx < du) ? __builtin_amdgcn_readlane(my, idx)
                                       : ZERO_ROW;       // SALU cselect; zero row
                    u[k] = *reinterpret_cast<const unsigned*>(
                        xb + (size_t)s * IN_F + lane * 2);
                }
                #pragma unroll
                for (int k = 0; k < 16; ++k) {
                    ax += bflo(u[k]);                    // padded rows add 0
                    ay += bfhi(u[k]);
                }
            }
            float inv = (du > 0) ? 1.0f / (float)du : 0.0f;
            ax *= inv; ay *= inv;
            int chunk = (lane >> 2) ^ row;               // XOR swizzle
            unsigned packed = (unsigned)(unsigned short)f2bf(ax)
                            | ((unsigned)(unsigned short)f2bf(ay) << 16);
            *reinterpret_cast<unsigned*>(reinterpret_cast<char*>(Ms)
                + row * 256 + chunk * 16 + (lane & 3) * 4) = packed;
        }

        // ---- issue branch1 A-frag loads BEFORE the barrier (latency hides) ----
        bf16x8 afrA[4];
        {
            const short* xrow = xb + (size_t)(r0 + row16) * IN_F + g * 8;
            #pragma unroll
            for (int ks = 0; ks < 4; ++ks)
                afrA[ks] = *reinterpret_cast<const bf16x8*>(xrow + ks * 32);
        }
        __syncthreads();

        // ---- dual stage1: two independent MFMA chains per nt ----
        bf16x8 afrB[4];
        #pragma unroll
        for (int ks = 0; ks < 4; ++ks) {
            int row = lane & 15, gg = lane >> 4;
            int chunk = (ks * 4 + gg) ^ row;
            afrB[ks] = *reinterpret_cast<const bf16x8*>(
                reinterpret_cast<const char*>(Ms) + row * 256 + chunk * 16);
        }
        #pragma unroll
        for (int i = 0; i < 4; ++i) {
            int nt = w * 4 + i;
            bf16x8 bA[4], bB[4];
            #pragma unroll
            for (int ks = 0; ks < 4; ++ks) {
                bA[ks] = *reinterpret_cast<const bf16x8*>(
                    F1a + ((size_t)(nt * 4 + ks) * 64 + lane) * 8);
                bB[ks] = *reinterpret_cast<const bf16x8*>(
                    Fc + ((size_t)(nt * 4 + ks) * 64 + lane) * 8);
            }
            f32x4 acc1 = {0.f, 0.f, 0.f, 0.f};
            f32x4 acc2 = {0.f, 0.f, 0.f, 0.f};
            #pragma unroll
            for (int ks = 0; ks < 4; ++ks) {
                acc1 = __builtin_amdgcn_mfma_f32_16x16x32_bf16(afrA[ks], bA[ks], acc1, 0, 0, 0);
                acc2 = __builtin_amdgcn_mfma_f32_16x16x32_bf16(afrB[ks], bB[ks], acc2, 0, 0, 0);
            }
            int col = nt * 16 + row16;
            float bias1 = b1a[col], bias2 = b2a[col];
            #pragma unroll
            for (int reg = 0; reg < 4; ++reg) {
                int hrow = g * 4 + reg;
                int off = hrow * 512 + ((((col >> 3) ^ hrow) & 31) * 16) + (col & 7) * 2;
                *reinterpret_cast<short*>(reinterpret_cast<char*>(Hs1) + off)
                    = f2bf(fmaxf(acc1[reg] + bias1, 0.0f));
                *reinterpret_cast<short*>(reinterpret_cast<char*>(Hs2) + off)
                    = f2bf(fmaxf(acc2[reg] + bias2, 0.0f));
            }
        }
        __syncthreads();

        // ---- dual stage2 + single store (tiles exactly cover 50000 rows) ----
        f32x4 o1 = {0.f, 0.f, 0.f, 0.f};
        f32x4 o2 = {0.f, 0.f, 0.f, 0.f};
        #pragma unroll
        for (int ks = 0; ks < 8; ++ks) {
            bf16x8 a1 = afrag_lds256(Hs1, lane, ks);
            bf16x8 b1 = *reinterpret_cast<const bf16x8*>(
                F1b + ((size_t)(w * 8 + ks) * 64 + lane) * 8);
            o1 = __builtin_amdgcn_mfma_f32_16x16x32_bf16(a1, b1, o1, 0, 0, 0);
            bf16x8 a2 = afrag_lds256(Hs2, lane, ks);
            bf16x8 b2 = *reinterpret_cast<const bf16x8*>(
                F2b + ((size_t)(w * 8 + ks) * 64 + lane) * 8);
            o2 = __builtin_amdgcn_mfma_f32_16x16x32_bf16(a2, b2, o2, 0, 0, 0);
        }
        {
            int col = w * 16 + row16;
            float bias = b1b[col] + b2b[col];
            #pragma unroll
            for (int reg = 0; reg < 4; ++reg) {
                long row = r0 + g * 4 + reg;
                out[row * OUT_F + col] = o1[reg] + o2[reg] + bias;
            }
        }
        __syncthreads();   // Ms/Hs reuse safety across tile iterations
    }
}

// ---------------------------------------------------------------------------
extern "C" void kernel_launch(void* const* d_in, const int* in_sizes, int n_in,
                              void* d_out, int out_size, void* d_ws, size_t ws_size,
                              hipStream_t stream)
{
    const float* x   = (const float*)d_in[0];
    const int*   ei  = (const int*)d_in[1];
    const float* Wsg = (const float*)d_in[2];
    const float* W1a = (const float*)d_in[3];
    const float* b1a = (const float*)d_in[4];
    const float* W1b = (const float*)d_in[5];
    const float* b1b = (const float*)d_in[6];
    const float* W2a = (const float*)d_in[7];
    const float* b2a = (const float*)d_in[8];
    const float* W2b = (const float*)d_in[9];
    const float* b2b = (const float*)d_in[10];
    float* out = (float*)d_out;

    // workspace layout (all 16B-aligned): ~18.8 MB total
    int* cursor = (int*)d_ws;                              // [N_PAD] (200 KB)
    unsigned short* esrc = (unsigned short*)(cursor + N_PAD);  // [N_PAD*56] = 5.6 MB
    short* F1a = (short*)(esrc + (size_t)N_PAD * SLOTS);   // 4096 chunks (64 KB)
    short* F1b = F1a + 4096 * 8;                           // 2048 chunks (32 KB)
    short* Fc  = F1b + 2048 * 8;                           // 4096 chunks (64 KB)
    short* F2b = Fc + 4096 * 8;                            // 2048 chunks (32 KB)
    short* xb  = F2b + 2048 * 8;                           // [N_PAD*128] bf16 (12.8 MB)
    int* sync_cnt = (int*)(xb + (size_t)N_PAD * IN_F);     // [64] barrier counters

    hipMemsetAsync(sync_cnt, 0, 256, stream);              // reset barrier counters
    mega_kernel<<<GRID, 256, 0, stream>>>(x, ei, Wsg, W2a, W1a, W1b, W2b,
                                          b1a, b1b, b2a, b2b,
                                          xb, esrc, cursor,
                                          F1a, F1b, Fc, F2b,
                                          sync_cnt, out);
}